// Round 11
// baseline (83.170 us; speedup 1.0000x reference)
//
#include <hip/hip_runtime.h>
#include <hip/hip_bf16.h>

// Match numpy float32 semantics exactly: no FMA contraction, fixed op order.
#pragma clang fp contract(off)

#define B_ 8
#define N_ 4096
#define C_ 128
#define K_ 16      // SAMPLE (output neighbors)
#define S_ 20      // SAMPLE_NUM (ball_query nsample)
#define NW 8       // queries per block (1 per wave) -> 4096 blocks, phase mixing
#define NSUB 4     // queries per LDS transpose pass (2 passes)
#define LP 129     // transpose pitch (words): odd -> conflict-light both sides
#define THREADS 512

typedef float f4 __attribute__((ext_vector_type(4)));

// slot s in [0,20) -> output position k = s - 1 - s/5, valid iff s>0 && s%5!=0

__global__ __launch_bounds__(THREADS, 4) void fused_kernel(const float* __restrict__ xyz,
                                                           const float* __restrict__ feat,
                                                           float* __restrict__ out_xyz,
                                                           float* __restrict__ out_feat) {
#pragma clang fp contract(off)
    // 64 KB union: phase A = packed (x,y,z,sq) per point; phase B = transpose buf
    __shared__ __align__(16) float smem[N_ * 4];
    __shared__ int sidx[NW * K_];
    f4* const pts = reinterpret_cast<f4*>(smem);

    const int w    = blockIdx.x;        // 0..4095
    const int b    = w & 7;             // XCD-align: batch b lives on XCD b
    const int n0   = (w >> 3) * NW;
    const int t    = threadIdx.x;
    const int wave = t >> 6;            // 0..7
    const int lane = t & 63;
    const float* xb = xyz + (size_t)b * (N_ * 3);

    // ---- stage whole batch as packed (x,y,z,sq); sq in exact ref op order ----
    for (int p = t; p < N_; p += THREADS) {
        const float x = xb[p * 3 + 0];
        const float y = xb[p * 3 + 1];
        const float z = xb[p * 3 + 2];
        const float sq = (x * x + y * y) + z * z;
        f4 v; v.x = x; v.y = y; v.z = z; v.w = sq;
        pts[p] = v;                      // stride-16B across lanes: conflict-free
    }
    __syncthreads();

    // ---------------- Phase A: 1 query per wave, 8 candidates/lane/iter -----
    {
        const int n  = n0 + wave;
        const f4 Q = pts[n];
        const float qx = Q.x, qy = Q.y, qz = Q.z;
        const float sqn = Q.w;

        int cnt = 0;
        int first = -1;
        int* out = sidx + wave * K_;
        const unsigned long long below = (1ull << lane) - 1ull;

        for (int base = 0; base < N_; base += 512) {
            bool in[8];
            unsigned long long M[8];
#pragma unroll
            for (int i = 0; i < 8; ++i) {
                const f4 P = pts[base + 64 * i + lane];   // conflict-free b128
                const float dt = (qx * P.x + qy * P.y) + qz * P.z;
                const float d2 = (sqn + P.w) - 2.0f * dt;
                in[i] = d2 < 256.0f;
                M[i]  = __ballot(in[i]);
            }

            if (cnt == 0) {   // wave-uniform: global first in-ball index
                int f = 0x7fffffff;
#pragma unroll
                for (int i = 0; i < 8; ++i) {
                    if (M[i]) {
                        const int c = base + 64 * i + (int)__builtin_ctzll(M[i]);
                        f = f < c ? f : c;
                    }
                }
                if (f != 0x7fffffff) first = f;
            }

            // in-order slots: candidate index = base + 64*i + lane (i-major)
            int run = cnt;
#pragma unroll
            for (int i = 0; i < 8; ++i) {
                const int s = run + (int)__popcll(M[i] & below);
                if (in[i] && s > 0 && s < S_ && (s % 5) != 0)
                    out[s - 1 - s / 5] = base + 64 * i + lane;
                run += (int)__popcll(M[i]);
            }
            cnt = run;
            if (cnt >= S_) break;   // wave-uniform exit
        }

        // pad slots [cnt, 20) with 'first'
        if (lane < S_ && lane >= cnt && lane > 0 && (lane % 5) != 0) {
            out[lane - 1 - lane / 5] = first;
        }
    }
    __syncthreads();   // sidx complete; pts still needed for xyz gather

    // ---------------- xyz gather (reads pts + sidx), nt streamed ------------
    if (t < 3 * NW * K_) {                 // 384 threads
        const int j  = t >> 7;             // 0..2
        const int r  = t & 127;
        const int nl = r >> 4;             // 0..7
        const int k  = r & 15;
        const f4 P = pts[sidx[nl * K_ + k]];
        const float val = (j == 0) ? P.x : (j == 1) ? P.y : P.z;
        __builtin_nontemporal_store(
            val, &out_xyz[((size_t)(b * 3 + j) * N_ + (n0 + nl)) * K_ + k]);
    }

    // ---------------- feature gather: 2 sub-tiles, software-pipelined -------
    const float* fb = feat + (size_t)b * N_ * C_;
    float* ob = out_feat + (size_t)b * C_ * N_ * K_ + (size_t)n0 * K_;

    // per-thread tile slice: 4 float4 (rows r = (t+512i)>>5, cols c0 = (t&31)*4)
    f4 v0, v1, v2, v3;
    const int rr0 = t >> 5,        cc0 = (t & 31) * 4;
    const int rr1 = (t + 512) >> 5;
    const int rr2 = (t + 1024) >> 5;
    const int rr3 = (t + 1536) >> 5;

#define LOADREGS(ST)                                                            \
    do {                                                                        \
        const int s_ = (ST) * NSUB;                                             \
        v0 = *reinterpret_cast<const f4*>(                                      \
            fb + (size_t)sidx[(s_ + (rr0 >> 4)) * K_ + (rr0 & 15)] * C_ + cc0); \
        v1 = *reinterpret_cast<const f4*>(                                      \
            fb + (size_t)sidx[(s_ + (rr1 >> 4)) * K_ + (rr1 & 15)] * C_ + cc0); \
        v2 = *reinterpret_cast<const f4*>(                                      \
            fb + (size_t)sidx[(s_ + (rr2 >> 4)) * K_ + (rr2 & 15)] * C_ + cc0); \
        v3 = *reinterpret_cast<const f4*>(                                      \
            fb + (size_t)sidx[(s_ + (rr3 >> 4)) * K_ + (rr3 & 15)] * C_ + cc0); \
    } while (0)

    LOADREGS(0);   // prologue (reads sidx + global only; smem untouched)

    for (int st = 0; st < NW / NSUB; ++st) {
        __syncthreads();   // previous drain (or xyz gather) done reading smem
        // commit tile st from regs into transpose buffer
        smem[rr0 * LP + cc0 + 0] = v0.x; smem[rr0 * LP + cc0 + 1] = v0.y;
        smem[rr0 * LP + cc0 + 2] = v0.z; smem[rr0 * LP + cc0 + 3] = v0.w;
        smem[rr1 * LP + cc0 + 0] = v1.x; smem[rr1 * LP + cc0 + 1] = v1.y;
        smem[rr1 * LP + cc0 + 2] = v1.z; smem[rr1 * LP + cc0 + 3] = v1.w;
        smem[rr2 * LP + cc0 + 0] = v2.x; smem[rr2 * LP + cc0 + 1] = v2.y;
        smem[rr2 * LP + cc0 + 2] = v2.z; smem[rr2 * LP + cc0 + 3] = v2.w;
        smem[rr3 * LP + cc0 + 0] = v3.x; smem[rr3 * LP + cc0 + 1] = v3.y;
        smem[rr3 * LP + cc0 + 2] = v3.z; smem[rr3 * LP + cc0 + 3] = v3.w;

        if (st + 1 < NW / NSUB) LOADREGS(st + 1);   // L2 latency hides under drain

        __syncthreads();
        // drain: nontemporal float4 stores, contiguous 64B per 4 rows;
        // LDS read bank = (r4 + c) % 32 with LP=129 -> ~2-way, free.
        for (int e = t; e < NSUB * K_ * C_ / 4; e += THREADS) {   // 2048 f4
            const int c  = e >> 4;          // 0..127
            const int r4 = (e & 15) * 4;    // 0,4,...,60
            f4 v;
            v.x = smem[(r4 + 0) * LP + c];
            v.y = smem[(r4 + 1) * LP + c];
            v.z = smem[(r4 + 2) * LP + c];
            v.w = smem[(r4 + 3) * LP + c];
            __builtin_nontemporal_store(
                v, reinterpret_cast<f4*>(
                       ob + (size_t)c * (N_ * K_) + (size_t)(st * NSUB) * K_ + r4));
        }
    }
#undef LOADREGS
}

extern "C" void kernel_launch(void* const* d_in, const int* in_sizes, int n_in,
                              void* d_out, int out_size, void* d_ws, size_t ws_size,
                              hipStream_t stream) {
    const float* xyz  = (const float*)d_in[0];   // (8, 4096, 3)
    const float* feat = (const float*)d_in[1];   // (8, 4096, 128)

    float* out_xyz  = (float*)d_out;                       // (8,3,4096,16)
    float* out_feat = out_xyz + (size_t)B_ * 3 * N_ * K_;  // (8,128,4096,16)

    // one block per (b, 8 consecutive queries); fused, no workspace
    hipLaunchKernelGGL(fused_kernel, dim3(B_ * N_ / NW), dim3(THREADS), 0, stream,
                       xyz, feat, out_xyz, out_feat);
}

// Round 12
// 66.465 us; speedup vs baseline: 1.2513x; 1.2513x over previous
//
#include <hip/hip_runtime.h>
#include <hip/hip_bf16.h>

// Match numpy float32 semantics exactly: no FMA contraction, fixed op order.
#pragma clang fp contract(off)

#define B_ 8
#define N_ 4096
#define HALF 2048  // points staged per A-pass (2 passes)
#define C_ 128
#define K_ 16      // SAMPLE (output neighbors)
#define S_ 20      // SAMPLE_NUM (ball_query nsample)
#define NW 8       // queries per block (1 per wave) -> 4096 blocks, phase mixing
#define NSUB 4     // queries per LDS transpose pass (2 passes)
#define LP 129     // transpose pitch (words): odd -> conflict-light both sides
#define THREADS 512

typedef float f4 __attribute__((ext_vector_type(4)));

// slot s in [0,20) -> output position k = s - 1 - s/5, valid iff s>0 && s%5!=0

__global__ __launch_bounds__(THREADS, 8) void fused_kernel(const float* __restrict__ xyz,
                                                           const float* __restrict__ feat,
                                                           float* __restrict__ out_xyz,
                                                           float* __restrict__ out_feat) {
#pragma clang fp contract(off)
    // ~33 KB union: phase A = packed (x,y,z,sq) half-batch; phase B = transpose
    __shared__ __align__(16) float smem[NSUB * K_ * LP];   // 8256 >= HALF*4=8192
    __shared__ int sidx[NW * K_];
    f4* const pts = reinterpret_cast<f4*>(smem);

    const int w    = blockIdx.x;        // 0..4095
    const int b    = w & 7;             // XCD-align: batch b lives on XCD b
    const int n0   = (w >> 3) * NW;
    const int t    = threadIdx.x;
    const int wave = t >> 6;            // 0..7
    const int lane = t & 63;
    const float* xb = xyz + (size_t)b * (N_ * 3);

    // ---------------- Phase A: 1 query per wave, two staged halves ----------
    {
        const int n  = n0 + wave;
        const float qx = xb[n * 3 + 0];
        const float qy = xb[n * 3 + 1];
        const float qz = xb[n * 3 + 2];
        const float sqn = (qx * qx + qy * qy) + qz * qz;   // exact ref op order

        int cnt = 0;
        int first = -1;
        bool done = false;
        int* out = sidx + wave * K_;
        const unsigned long long below = (1ull << lane) - 1ull;

        for (int half = 0; half < 2; ++half) {
            __syncthreads();   // prior half's scan reads complete (no-op @ half 0)
            // stage packed (x,y,z,sq); sq computed once, exact ref op order
            for (int p = t; p < HALF; p += THREADS) {
                const int gp = half * HALF + p;
                const float x = xb[gp * 3 + 0];
                const float y = xb[gp * 3 + 1];
                const float z = xb[gp * 3 + 2];
                const float sq = (x * x + y * y) + z * z;
                f4 v; v.x = x; v.y = y; v.z = z; v.w = sq;
                pts[p] = v;              // stride-16B across lanes: conflict-free
            }
            __syncthreads();             // half staged

            if (done) continue;          // wave-uniform; still hits barriers

            for (int base = 0; base < HALF; base += 512) {
                const int gbase = half * HALF + base;
                bool in[8];
                unsigned long long M[8];
#pragma unroll
                for (int i = 0; i < 8; ++i) {
                    const f4 P = pts[base + 64 * i + lane];   // 1 b128, no conflict
                    const float dt = (qx * P.x + qy * P.y) + qz * P.z;
                    const float d2 = (sqn + P.w) - 2.0f * dt;
                    in[i] = d2 < 256.0f;
                    M[i]  = __ballot(in[i]);
                }

                if (cnt == 0) {   // wave-uniform: global first in-ball index
                    int f = 0x7fffffff;
#pragma unroll
                    for (int i = 0; i < 8; ++i) {
                        if (M[i]) {
                            const int c = gbase + 64 * i + (int)__builtin_ctzll(M[i]);
                            f = f < c ? f : c;
                        }
                    }
                    if (f != 0x7fffffff) first = f;
                }

                // in-order slots: candidate index = gbase + 64*i + lane (i-major)
                int run = cnt;
#pragma unroll
                for (int i = 0; i < 8; ++i) {
                    const int s = run + (int)__popcll(M[i] & below);
                    if (in[i] && s > 0 && s < S_ && (s % 5) != 0)
                        out[s - 1 - s / 5] = gbase + 64 * i + lane;
                    run += (int)__popcll(M[i]);
                }
                cnt = run;
                if (cnt >= S_) { done = true; break; }   // wave-uniform
            }
        }

        // pad slots [cnt, 20) with 'first'
        if (lane < S_ && lane >= cnt && lane > 0 && (lane % 5) != 0) {
            out[lane - 1 - lane / 5] = first;
        }
    }
    __syncthreads();   // sidx complete; all scan reads of smem done

    // ---------------- xyz gather (global scattered reads, L2-hot) -----------
    if (t < 3 * NW * K_) {                 // 384 threads
        const int j  = t >> 7;             // 0..2
        const int r  = t & 127;
        const int nl = r >> 4;             // 0..7
        const int k  = r & 15;
        __builtin_nontemporal_store(
            xb[(size_t)sidx[nl * K_ + k] * 3 + j],
            &out_xyz[((size_t)(b * 3 + j) * N_ + (n0 + nl)) * K_ + k]);
    }

    // ---------------- feature gather: 2 sub-tiles, software-pipelined -------
    const float* fb = feat + (size_t)b * N_ * C_;
    float* ob = out_feat + (size_t)b * C_ * N_ * K_ + (size_t)n0 * K_;

    // per-thread tile slice: 4 float4 (rows r = (t+512i)>>5, cols c0 = (t&31)*4)
    f4 v0, v1, v2, v3;
    const int rr0 = t >> 5,        cc0 = (t & 31) * 4;
    const int rr1 = (t + 512) >> 5;
    const int rr2 = (t + 1024) >> 5;
    const int rr3 = (t + 1536) >> 5;

#define LOADREGS(ST)                                                            \
    do {                                                                        \
        const int s_ = (ST) * NSUB;                                             \
        v0 = *reinterpret_cast<const f4*>(                                      \
            fb + (size_t)sidx[(s_ + (rr0 >> 4)) * K_ + (rr0 & 15)] * C_ + cc0); \
        v1 = *reinterpret_cast<const f4*>(                                      \
            fb + (size_t)sidx[(s_ + (rr1 >> 4)) * K_ + (rr1 & 15)] * C_ + cc0); \
        v2 = *reinterpret_cast<const f4*>(                                      \
            fb + (size_t)sidx[(s_ + (rr2 >> 4)) * K_ + (rr2 & 15)] * C_ + cc0); \
        v3 = *reinterpret_cast<const f4*>(                                      \
            fb + (size_t)sidx[(s_ + (rr3 >> 4)) * K_ + (rr3 & 15)] * C_ + cc0); \
    } while (0)

    LOADREGS(0);   // prologue (reads sidx + global only; smem untouched)

    for (int st = 0; st < NW / NSUB; ++st) {
        __syncthreads();   // previous drain (or phase A) done with smem
        // commit tile st from regs into transpose buffer
        smem[rr0 * LP + cc0 + 0] = v0.x; smem[rr0 * LP + cc0 + 1] = v0.y;
        smem[rr0 * LP + cc0 + 2] = v0.z; smem[rr0 * LP + cc0 + 3] = v0.w;
        smem[rr1 * LP + cc0 + 0] = v1.x; smem[rr1 * LP + cc0 + 1] = v1.y;
        smem[rr1 * LP + cc0 + 2] = v1.z; smem[rr1 * LP + cc0 + 3] = v1.w;
        smem[rr2 * LP + cc0 + 0] = v2.x; smem[rr2 * LP + cc0 + 1] = v2.y;
        smem[rr2 * LP + cc0 + 2] = v2.z; smem[rr2 * LP + cc0 + 3] = v2.w;
        smem[rr3 * LP + cc0 + 0] = v3.x; smem[rr3 * LP + cc0 + 1] = v3.y;
        smem[rr3 * LP + cc0 + 2] = v3.z; smem[rr3 * LP + cc0 + 3] = v3.w;

        if (st + 1 < NW / NSUB) LOADREGS(st + 1);   // L2 latency hides under drain

        __syncthreads();
        // drain: nontemporal float4 stores, contiguous 64B per 4 rows;
        // LDS read bank = (r4 + c) % 32 with LP=129 -> ~2-way, free.
        for (int e = t; e < NSUB * K_ * C_ / 4; e += THREADS) {   // 2048 f4
            const int c  = e >> 4;          // 0..127
            const int r4 = (e & 15) * 4;    // 0,4,...,60
            f4 v;
            v.x = smem[(r4 + 0) * LP + c];
            v.y = smem[(r4 + 1) * LP + c];
            v.z = smem[(r4 + 2) * LP + c];
            v.w = smem[(r4 + 3) * LP + c];
            __builtin_nontemporal_store(
                v, reinterpret_cast<f4*>(
                       ob + (size_t)c * (N_ * K_) + (size_t)(st * NSUB) * K_ + r4));
        }
    }
#undef LOADREGS
}

extern "C" void kernel_launch(void* const* d_in, const int* in_sizes, int n_in,
                              void* d_out, int out_size, void* d_ws, size_t ws_size,
                              hipStream_t stream) {
    const float* xyz  = (const float*)d_in[0];   // (8, 4096, 3)
    const float* feat = (const float*)d_in[1];   // (8, 4096, 128)

    float* out_xyz  = (float*)d_out;                       // (8,3,4096,16)
    float* out_feat = out_xyz + (size_t)B_ * 3 * N_ * K_;  // (8,128,4096,16)

    // one block per (b, 8 consecutive queries); fused, no workspace
    hipLaunchKernelGGL(fused_kernel, dim3(B_ * N_ / NW), dim3(THREADS), 0, stream,
                       xyz, feat, out_xyz, out_feat);
}